// Round 1
// baseline (5801.465 us; speedup 1.0000x reference)
//
#include <hip/hip_runtime.h>

constexpr int Nn = 50000;
constexpr int Ee = 800000;
constexpr int Qq = 2000000;
constexpr int Gg = 64;
constexpr int Ll = 3;
constexpr int Hh = 128;

// ---------------- compact useful quadruplets (k_idx < Nn) ----------------
__global__ void k_compact(const int* __restrict__ kidx, int* __restrict__ list,
                          int* __restrict__ cnt) {
    int q = blockIdx.x * blockDim.x + threadIdx.x;
    if (q < Qq && kidx[q] < Nn) {
        int p = atomicAdd(cnt, 1);
        list[p] = q;
    }
}

// ---------------- generic fused 2-layer MLP on a 32-row LDS tile ----------------
// 256 threads: thread t owns rows r0..r0+7 (r0=(t>>6)*8), cols jj,jj+1 (jj=(t&63)*2)
template<int D1, int SIN>
__device__ __forceinline__ void mlp2_tile(const float* in_t, float* t_t,
    const float* __restrict__ Wa, const float* __restrict__ ba,
    const float* __restrict__ Wb, const float* __restrict__ bb,
    float accOut[8][2])
{
    const int tid = threadIdx.x;
    const int jj = (tid & 63) * 2;
    const int r0 = (tid >> 6) * 8;
    float acc[8][2];
#pragma unroll
    for (int r = 0; r < 8; ++r) { acc[r][0] = ba[jj]; acc[r][1] = ba[jj + 1]; }
    constexpr int D1_4 = D1 & ~3;
    for (int d0 = 0; d0 < D1_4; d0 += 4) {
        float4 a[8];
#pragma unroll
        for (int r = 0; r < 8; ++r)
            a[r] = *(const float4*)&in_t[(r0 + r) * SIN + d0];
        float2 w0 = *(const float2*)&Wa[(d0 + 0) * Hh + jj];
        float2 w1 = *(const float2*)&Wa[(d0 + 1) * Hh + jj];
        float2 w2 = *(const float2*)&Wa[(d0 + 2) * Hh + jj];
        float2 w3 = *(const float2*)&Wa[(d0 + 3) * Hh + jj];
#pragma unroll
        for (int r = 0; r < 8; ++r) {
            acc[r][0] = fmaf(a[r].x, w0.x, acc[r][0]);
            acc[r][1] = fmaf(a[r].x, w0.y, acc[r][1]);
            acc[r][0] = fmaf(a[r].y, w1.x, acc[r][0]);
            acc[r][1] = fmaf(a[r].y, w1.y, acc[r][1]);
            acc[r][0] = fmaf(a[r].z, w2.x, acc[r][0]);
            acc[r][1] = fmaf(a[r].z, w2.y, acc[r][1]);
            acc[r][0] = fmaf(a[r].w, w3.x, acc[r][0]);
            acc[r][1] = fmaf(a[r].w, w3.y, acc[r][1]);
        }
    }
    if constexpr (D1_4 < D1) {
        for (int d0 = D1_4; d0 < D1; ++d0) {
            float2 w = *(const float2*)&Wa[d0 * Hh + jj];
#pragma unroll
            for (int r = 0; r < 8; ++r) {
                float av = in_t[(r0 + r) * SIN + d0];
                acc[r][0] = fmaf(av, w.x, acc[r][0]);
                acc[r][1] = fmaf(av, w.y, acc[r][1]);
            }
        }
    }
#pragma unroll
    for (int r = 0; r < 8; ++r) {
        float2 v;
        v.x = fmaxf(acc[r][0], 0.f);
        v.y = fmaxf(acc[r][1], 0.f);
        *(float2*)&t_t[(r0 + r) * 132 + jj] = v;
    }
    __syncthreads();
#pragma unroll
    for (int r = 0; r < 8; ++r) { accOut[r][0] = bb[jj]; accOut[r][1] = bb[jj + 1]; }
    for (int d0 = 0; d0 < Hh; d0 += 4) {
        float4 a[8];
#pragma unroll
        for (int r = 0; r < 8; ++r)
            a[r] = *(const float4*)&t_t[(r0 + r) * 132 + d0];
        float2 w0 = *(const float2*)&Wb[(d0 + 0) * Hh + jj];
        float2 w1 = *(const float2*)&Wb[(d0 + 1) * Hh + jj];
        float2 w2 = *(const float2*)&Wb[(d0 + 2) * Hh + jj];
        float2 w3 = *(const float2*)&Wb[(d0 + 3) * Hh + jj];
#pragma unroll
        for (int r = 0; r < 8; ++r) {
            accOut[r][0] = fmaf(a[r].x, w0.x, accOut[r][0]);
            accOut[r][1] = fmaf(a[r].x, w0.y, accOut[r][1]);
            accOut[r][0] = fmaf(a[r].y, w1.x, accOut[r][0]);
            accOut[r][1] = fmaf(a[r].y, w1.y, accOut[r][1]);
            accOut[r][0] = fmaf(a[r].z, w2.x, accOut[r][0]);
            accOut[r][1] = fmaf(a[r].z, w2.y, accOut[r][1]);
            accOut[r][0] = fmaf(a[r].w, w3.x, accOut[r][0]);
            accOut[r][1] = fmaf(a[r].w, w3.y, accOut[r][1]);
        }
    }
}

// ---------------- quadruplet message MLP + scatter into agg2[k_idx] ----------------
__global__ __launch_bounds__(256) void k_quad(
    const float* __restrict__ h,
    const float* __restrict__ rbf, const float* __restrict__ cbf, const float* __restrict__ sbf,
    const int* __restrict__ l_idx, const int* __restrict__ k_idx,
    const int* __restrict__ list, const int* __restrict__ cnt,
    const float* __restrict__ Wa, const float* __restrict__ ba,
    const float* __restrict__ Wb, const float* __restrict__ bb,
    float* __restrict__ agg2)
{
    __shared__ float in_t[32 * 148];
    __shared__ float t_t[32 * 132];
    __shared__ int rowq[32];
    __shared__ int rowk[32];
    const int Qu = *cnt;
    const int m0 = blockIdx.x * 32;
    if (m0 >= Qu) return;
    const int tid = threadIdx.x;
    if (tid < 32) {
        int m = m0 + tid;
        int q = list[min(m, Qu - 1)];
        rowq[tid] = q;
        rowk[tid] = (m < Qu) ? k_idx[q] : -1;
    }
    __syncthreads();
    {
        const int r = tid >> 3;
        const int l8 = tid & 7;
        int q = rowq[r];
        int li = l_idx[q];
        int ki = k_idx[q];
        const float* hrow = h + (size_t)li * Hh;
        for (int c0 = l8 * 4; c0 < Hh; c0 += 32)
            *(float4*)&in_t[r * 148 + c0] = *(const float4*)&hrow[c0];
        for (int idx = l8; idx < 20; idx += 8) {
            float v = 0.f;
            if (idx < 6)       v = rbf[(size_t)ki * 6 + idx];
            else if (idx < 12) v = cbf[(size_t)q * 6 + (idx - 6)];
            else if (idx < 18) v = sbf[(size_t)q * 6 + (idx - 12)];
            in_t[r * 148 + Hh + idx] = v;
        }
    }
    __syncthreads();
    float accOut[8][2];
    mlp2_tile<146, 148>(in_t, t_t, Wa, ba, Wb, bb, accOut);
    const int jj = (tid & 63) * 2;
    const int r0 = (tid >> 6) * 8;
#pragma unroll
    for (int rr = 0; rr < 8; ++rr) {
        int tgt = rowk[r0 + rr];
        if (tgt >= 0) {
            atomicAdd(&agg2[(size_t)tgt * Hh + jj],     accOut[rr][0]);
            atomicAdd(&agg2[(size_t)tgt * Hh + jj + 1], accOut[rr][1]);
        }
    }
}

// ---------------- edge MLP + scatter into aggr[dst] ----------------
__global__ __launch_bounds__(256) void k_edge(
    const float* __restrict__ h, const float* __restrict__ agg2,
    const int* __restrict__ src, const int* __restrict__ dst,
    const float* __restrict__ Wa, const float* __restrict__ ba,
    const float* __restrict__ Wb, const float* __restrict__ bb,
    float* __restrict__ aggr)
{
    __shared__ float in_t[32 * 260];
    __shared__ float t_t[32 * 132];
    __shared__ int rowd[32];
    const int m0 = blockIdx.x * 32;   // Ee % 32 == 0: all tiles full
    const int tid = threadIdx.x;
    {
        const int r = tid >> 3;
        const int l8 = tid & 7;
        int e = m0 + r;
        int s = src[e];
        int d = dst[e];
        if (l8 == 0) rowd[r] = d;
        const float* hrow = h + (size_t)s * Hh;
        const float* arow = agg2 + (size_t)d * Hh;
        for (int c0 = l8 * 4; c0 < Hh; c0 += 32) {
            *(float4*)&in_t[r * 260 + c0]       = *(const float4*)&hrow[c0];
            *(float4*)&in_t[r * 260 + Hh + c0]  = *(const float4*)&arow[c0];
        }
    }
    __syncthreads();
    float accOut[8][2];
    mlp2_tile<256, 260>(in_t, t_t, Wa, ba, Wb, bb, accOut);
    const int jj = (tid & 63) * 2;
    const int r0 = (tid >> 6) * 8;
#pragma unroll
    for (int rr = 0; rr < 8; ++rr) {
        int tgt = rowd[r0 + rr];
        atomicAdd(&aggr[(size_t)tgt * Hh + jj],     accOut[rr][0]);
        atomicAdd(&aggr[(size_t)tgt * Hh + jj + 1], accOut[rr][1]);
    }
}

// ---------------- node update MLP ----------------
__global__ __launch_bounds__(256) void k_node(
    const float* __restrict__ h, const float* __restrict__ aggr,
    const float* __restrict__ Wa, const float* __restrict__ ba,
    const float* __restrict__ Wb, const float* __restrict__ bb,
    float* __restrict__ hnew)
{
    __shared__ float in_t[32 * 260];
    __shared__ float t_t[32 * 132];
    const int m0 = blockIdx.x * 32;
    const int tid = threadIdx.x;
    {
        const int r = tid >> 3;
        const int l8 = tid & 7;
        int n = m0 + r;
        int nc = min(n, Nn - 1);
        const float* hrow = h + (size_t)nc * Hh;
        const float* arow = aggr + (size_t)nc * Hh;
        for (int c0 = l8 * 4; c0 < Hh; c0 += 32) {
            *(float4*)&in_t[r * 260 + c0]      = *(const float4*)&hrow[c0];
            *(float4*)&in_t[r * 260 + Hh + c0] = *(const float4*)&arow[c0];
        }
    }
    __syncthreads();
    float accOut[8][2];
    mlp2_tile<256, 260>(in_t, t_t, Wa, ba, Wb, bb, accOut);
    const int jj = (tid & 63) * 2;
    const int r0 = (tid >> 6) * 8;
#pragma unroll
    for (int rr = 0; rr < 8; ++rr) {
        int n = m0 + r0 + rr;
        if (n < Nn) {
            float2 v; v.x = accOut[rr][0]; v.y = accOut[rr][1];
            *(float2*)&hnew[(size_t)n * Hh + jj] = v;
        }
    }
}

// ---------------- global mean pool (atomic) ----------------
__global__ void k_pool(const float* __restrict__ h, const int* __restrict__ batch,
                       float* __restrict__ pooled, float* __restrict__ cntg) {
    int i = blockIdx.x * blockDim.x + threadIdx.x;
    if (i >= Nn * 32) return;
    int n = i >> 5;
    int cc = (i & 31) * 4;
    int b = batch[n];
    float4 v = *(const float4*)&h[(size_t)n * Hh + cc];
    atomicAdd(&pooled[b * Hh + cc + 0], v.x);
    atomicAdd(&pooled[b * Hh + cc + 1], v.y);
    atomicAdd(&pooled[b * Hh + cc + 2], v.z);
    atomicAdd(&pooled[b * Hh + cc + 3], v.w);
    if (cc == 0) atomicAdd(&cntg[b], 1.f);
}

// ---------------- final per-graph MLP ----------------
__global__ __launch_bounds__(128) void k_final(
    const float* __restrict__ pooled, const float* __restrict__ cntg,
    const float* __restrict__ Woa, const float* __restrict__ boa,
    const float* __restrict__ Wob, const float* __restrict__ bob,
    float* __restrict__ out)
{
    __shared__ float p[128];
    __shared__ float t[128];
    __shared__ float red[128];
    const int g = blockIdx.x;
    const int j = threadIdx.x;
    float c = fmaxf(cntg[g], 1.f);
    p[j] = fmaxf(pooled[g * Hh + j] / c, 0.f);
    __syncthreads();
    float acc = boa[j];
    for (int d = 0; d < Hh; ++d) acc = fmaf(p[d], Woa[d * Hh + j], acc);
    t[j] = fmaxf(acc, 0.f);
    __syncthreads();
    red[j] = t[j] * Wob[j];
    __syncthreads();
    for (int s = 64; s > 0; s >>= 1) {
        if (j < s) red[j] += red[j + s];
        __syncthreads();
    }
    if (j == 0) out[g] = red[0] + bob[0];
}

extern "C" void kernel_launch(void* const* d_in, const int* in_sizes, int n_in,
                              void* d_out, int out_size, void* d_ws, size_t ws_size,
                              hipStream_t stream) {
    const float* x     = (const float*)d_in[0];
    const float* rbf   = (const float*)d_in[1];
    const float* cbf   = (const float*)d_in[2];
    const float* sbf   = (const float*)d_in[3];
    const int*   eidx  = (const int*)d_in[4];
    const int*   l_idx = (const int*)d_in[5];
    const int*   k_idx = (const int*)d_in[6];
    const int*   batch = (const int*)d_in[7];
    const float* W_e1a = (const float*)d_in[8];
    const float* b_e1a = (const float*)d_in[9];
    const float* W_e1b = (const float*)d_in[10];
    const float* b_e1b = (const float*)d_in[11];
    const float* W_e2a = (const float*)d_in[12];
    const float* b_e2a = (const float*)d_in[13];
    const float* W_e2b = (const float*)d_in[14];
    const float* b_e2b = (const float*)d_in[15];
    const float* W_na  = (const float*)d_in[16];
    const float* b_na  = (const float*)d_in[17];
    const float* W_nb  = (const float*)d_in[18];
    const float* b_nb  = (const float*)d_in[19];
    const float* W_oa  = (const float*)d_in[20];
    const float* b_oa  = (const float*)d_in[21];
    const float* W_ob  = (const float*)d_in[22];
    const float* b_ob  = (const float*)d_in[23];

    const int* src = eidx;
    const int* dst = eidx + Ee;

    const size_t NH = (size_t)Nn * Hh * sizeof(float);
    char* w = (char*)d_ws;
    float* h0     = (float*)w; w += NH;
    float* h1     = (float*)w; w += NH;
    float* agg2   = (float*)w; w += NH;
    float* aggr   = (float*)w; w += NH;
    float* pooled = (float*)w; w += (size_t)Gg * Hh * sizeof(float);
    float* cntg   = (float*)w; w += (size_t)Gg * sizeof(float);
    int*   qlist  = (int*)w;   w += (size_t)Qq * sizeof(int);
    int*   qcnt   = (int*)w;   w += sizeof(int);

    hipMemsetAsync(qcnt, 0, sizeof(int), stream);
    k_compact<<<(Qq + 255) / 256, 256, 0, stream>>>(k_idx, qlist, qcnt);
    hipMemcpyAsync(h0, x, NH, hipMemcpyDeviceToDevice, stream);

    float* bufs[2] = { h0, h1 };
    int cur = 0;
    for (int p = 0; p < Ll; ++p) {
        hipMemsetAsync(agg2, 0, NH, stream);
        hipMemsetAsync(aggr, 0, NH, stream);
        k_quad<<<Qq / 32, 256, 0, stream>>>(bufs[cur], rbf, cbf, sbf, l_idx, k_idx,
            qlist, qcnt,
            W_e1a + (size_t)p * 146 * Hh, b_e1a + (size_t)p * Hh,
            W_e1b + (size_t)p * Hh * Hh,  b_e1b + (size_t)p * Hh, agg2);
        k_edge<<<Ee / 32, 256, 0, stream>>>(bufs[cur], agg2, src, dst,
            W_e2a + (size_t)p * 256 * Hh, b_e2a + (size_t)p * Hh,
            W_e2b + (size_t)p * Hh * Hh,  b_e2b + (size_t)p * Hh, aggr);
        k_node<<<(Nn + 31) / 32, 256, 0, stream>>>(bufs[cur], aggr,
            W_na + (size_t)p * 256 * Hh, b_na + (size_t)p * Hh,
            W_nb + (size_t)p * Hh * Hh,  b_nb + (size_t)p * Hh, bufs[cur ^ 1]);
        cur ^= 1;
    }
    hipMemsetAsync(pooled, 0, (size_t)Gg * Hh * sizeof(float), stream);
    hipMemsetAsync(cntg, 0, (size_t)Gg * sizeof(float), stream);
    k_pool<<<(Nn * 32 + 255) / 256, 256, 0, stream>>>(bufs[cur], batch, pooled, cntg);
    k_final<<<Gg, 128, 0, stream>>>(pooled, cntg, W_oa, b_oa, W_ob, b_ob, (float*)d_out);
}

// Round 2
// 2434.501 us; speedup vs baseline: 2.3830x; 2.3830x over previous
//
#include <hip/hip_runtime.h>

constexpr int Nn = 50000;
constexpr int Ee = 800000;
constexpr int Qq = 2000000;
constexpr int Gg = 64;
constexpr int Hh = 128;

typedef short bf16x8 __attribute__((ext_vector_type(8)));
typedef float f32x4  __attribute__((ext_vector_type(4)));

__device__ __forceinline__ unsigned short f2bf(float f) {
    unsigned u = __builtin_bit_cast(unsigned, f);
    u += 0x7FFFu + ((u >> 16) & 1u);
    return (unsigned short)(u >> 16);
}
__device__ __forceinline__ float bf2f(unsigned short s) {
    unsigned u = ((unsigned)s) << 16;
    return __builtin_bit_cast(float, u);
}

// ---------------- compact useful quadruplets (k_idx < Nn) ----------------
__global__ void k_compact(const int* __restrict__ kidx, int* __restrict__ list,
                          int* __restrict__ cnt) {
    int q = blockIdx.x * blockDim.x + threadIdx.x;
    if (q < Qq && kidx[q] < Nn) {
        int p = atomicAdd(cnt, 1);
        list[p] = q;
    }
}

// ---------------- weight transpose+pad to bf16 [128][Kp] (k-contiguous) ----------------
__global__ void k_wt(const float* __restrict__ in, unsigned short* __restrict__ out,
                     int K, int Kp) {
    int idx = blockIdx.x * blockDim.x + threadIdx.x;
    if (idx >= 128 * Kp) return;
    int n = idx / Kp, k = idx - n * Kp;
    out[idx] = (k < K) ? f2bf(in[(size_t)k * 128 + n]) : (unsigned short)0;
}

// ---------------- x -> bf16 h0 ----------------
__global__ void k_h0(const float* __restrict__ x, unsigned short* __restrict__ hb) {
    int idx = blockIdx.x * blockDim.x + threadIdx.x;
    if (idx < Nn * Hh) hb[idx] = f2bf(x[idx]);
}

// ---------------- fused 2-layer MFMA MLP on a 64-row tile ----------------
// 256 threads = 4 waves; wave w -> output cols [32w,32w+32); 4 row-tiles of 16.
// A2 may alias A1 (barriers guard the overwrite).
template<int K1P, int SA1>
__device__ __forceinline__ void mfma_mlp2(
    const unsigned short* A1, unsigned short* A2,
    const unsigned short* __restrict__ Wa, const float* __restrict__ ba,
    const unsigned short* __restrict__ Wb, const float* __restrict__ bb,
    float accOut[4][2][4])
{
    const int tid  = threadIdx.x;
    const int lane = tid & 63;
    const int wid  = tid >> 6;
    const int nb   = wid * 32;
    const int rA   = lane & 15;
    const int kg   = lane >> 4;     // 0..3

    f32x4 acc[4][2];
#pragma unroll
    for (int rt = 0; rt < 4; ++rt)
#pragma unroll
        for (int ct = 0; ct < 2; ++ct)
            acc[rt][ct] = (f32x4){0.f, 0.f, 0.f, 0.f};

#pragma unroll
    for (int ks = 0; ks < K1P / 32; ++ks) {
        const int k0 = ks * 32 + kg * 8;
        bf16x8 b0 = *(const bf16x8*)&Wa[(size_t)(nb + rA) * K1P + k0];
        bf16x8 b1 = *(const bf16x8*)&Wa[(size_t)(nb + 16 + rA) * K1P + k0];
#pragma unroll
        for (int rt = 0; rt < 4; ++rt) {
            bf16x8 a = *(const bf16x8*)&A1[(rt * 16 + rA) * SA1 + k0];
            acc[rt][0] = __builtin_amdgcn_mfma_f32_16x16x32_bf16(a, b0, acc[rt][0], 0, 0, 0);
            acc[rt][1] = __builtin_amdgcn_mfma_f32_16x16x32_bf16(a, b1, acc[rt][1], 0, 0, 0);
        }
    }
    __syncthreads();            // all A1 reads done before A2 overwrite
#pragma unroll
    for (int rt = 0; rt < 4; ++rt)
#pragma unroll
        for (int ct = 0; ct < 2; ++ct) {
            int col = nb + ct * 16 + rA;
            float bias = ba[col];
#pragma unroll
            for (int i = 0; i < 4; ++i) {
                int row = rt * 16 + kg * 4 + i;
                A2[row * 136 + col] = f2bf(fmaxf(acc[rt][ct][i] + bias, 0.f));
            }
        }
    __syncthreads();

    f32x4 acc2[4][2];
#pragma unroll
    for (int rt = 0; rt < 4; ++rt)
#pragma unroll
        for (int ct = 0; ct < 2; ++ct)
            acc2[rt][ct] = (f32x4){0.f, 0.f, 0.f, 0.f};

#pragma unroll
    for (int ks = 0; ks < 4; ++ks) {
        const int k0 = ks * 32 + kg * 8;
        bf16x8 b0 = *(const bf16x8*)&Wb[(size_t)(nb + rA) * 128 + k0];
        bf16x8 b1 = *(const bf16x8*)&Wb[(size_t)(nb + 16 + rA) * 128 + k0];
#pragma unroll
        for (int rt = 0; rt < 4; ++rt) {
            bf16x8 a = *(const bf16x8*)&A2[(rt * 16 + rA) * 136 + k0];
            acc2[rt][0] = __builtin_amdgcn_mfma_f32_16x16x32_bf16(a, b0, acc2[rt][0], 0, 0, 0);
            acc2[rt][1] = __builtin_amdgcn_mfma_f32_16x16x32_bf16(a, b1, acc2[rt][1], 0, 0, 0);
        }
    }
#pragma unroll
    for (int rt = 0; rt < 4; ++rt)
#pragma unroll
        for (int ct = 0; ct < 2; ++ct) {
            int col = nb + ct * 16 + rA;
            float bias = bb[col];
#pragma unroll
            for (int i = 0; i < 4; ++i)
                accOut[rt][ct][i] = acc2[rt][ct][i] + bias;
        }
}

// ---------------- quadruplet message MLP + scatter into agg2[k_idx] ----------------
__global__ __launch_bounds__(256) void k_quad(
    const unsigned short* __restrict__ hb,
    const float* __restrict__ rbf, const float* __restrict__ cbf, const float* __restrict__ sbf,
    const int* __restrict__ l_idx, const int* __restrict__ k_idx,
    const int* __restrict__ list, const int* __restrict__ cnt,
    const unsigned short* __restrict__ Wa, const float* __restrict__ ba,
    const unsigned short* __restrict__ Wb, const float* __restrict__ bb,
    float* __restrict__ agg2)
{
    __shared__ unsigned short A1[64 * 168];
    __shared__ int rqi[64], rli[64], rki[64];
    const int Qu = *cnt;
    const int m0 = blockIdx.x * 64;
    if (m0 >= Qu) return;
    const int tid = threadIdx.x;
    if (tid < 64) {
        int m = m0 + tid;
        int q = list[min(m, Qu - 1)];
        rqi[tid] = q; rli[tid] = l_idx[q]; rki[tid] = k_idx[q];
    }
    __syncthreads();
    for (int i = tid; i < 64 * 16; i += 256) {
        int row = i >> 4, ch = i & 15;
        *(uint4*)&A1[row * 168 + ch * 8] =
            *(const uint4*)&hb[(size_t)rli[row] * Hh + ch * 8];
    }
    for (int i = tid; i < 64 * 32; i += 256) {
        int row = i >> 5, c = i & 31;
        int q = rqi[row], ki = rki[row];
        float v = 0.f;
        if (c < 6)       v = rbf[(size_t)ki * 6 + c];
        else if (c < 12) v = cbf[(size_t)q * 6 + (c - 6)];
        else if (c < 18) v = sbf[(size_t)q * 6 + (c - 12)];
        A1[row * 168 + 128 + c] = f2bf(v);
    }
    __syncthreads();
    float accOut[4][2][4];
    mfma_mlp2<160, 168>(A1, A1, Wa, ba, Wb, bb, accOut);
    const int lane = tid & 63;
    const int nb = (tid >> 6) * 32;
    const int rA = lane & 15, kg = lane >> 4;
#pragma unroll
    for (int rt = 0; rt < 4; ++rt)
#pragma unroll
        for (int ct = 0; ct < 2; ++ct) {
            int col = nb + ct * 16 + rA;
#pragma unroll
            for (int i = 0; i < 4; ++i) {
                int row = rt * 16 + kg * 4 + i;
                if (m0 + row < Qu)
                    atomicAdd(&agg2[(size_t)rki[row] * Hh + col], accOut[rt][ct][i]);
            }
        }
}

// ---------------- edge MLP + scatter into aggr[dst] ----------------
__global__ __launch_bounds__(256) void k_edge(
    const unsigned short* __restrict__ hb, const float* __restrict__ agg2,
    const int* __restrict__ src, const int* __restrict__ dst,
    const unsigned short* __restrict__ Wa, const float* __restrict__ ba,
    const unsigned short* __restrict__ Wb, const float* __restrict__ bb,
    float* __restrict__ aggr)
{
    __shared__ unsigned short A1[64 * 264];
    __shared__ int rs[64], rd[64];
    const int m0 = blockIdx.x * 64;         // Ee % 64 == 0
    const int tid = threadIdx.x;
    if (tid < 64) { rs[tid] = src[m0 + tid]; rd[tid] = dst[m0 + tid]; }
    __syncthreads();
    for (int i = tid; i < 64 * 16; i += 256) {
        int row = i >> 4, ch = i & 15;
        *(uint4*)&A1[row * 264 + ch * 8] =
            *(const uint4*)&hb[(size_t)rs[row] * Hh + ch * 8];
    }
    for (int i = tid; i < 64 * 32; i += 256) {
        int row = i >> 5, c = i & 31;
        float4 v = *(const float4*)&agg2[(size_t)rd[row] * Hh + c * 4];
        ushort4 o;
        o.x = f2bf(v.x); o.y = f2bf(v.y); o.z = f2bf(v.z); o.w = f2bf(v.w);
        *(ushort4*)&A1[row * 264 + 128 + c * 4] = o;
    }
    __syncthreads();
    float accOut[4][2][4];
    mfma_mlp2<256, 264>(A1, A1, Wa, ba, Wb, bb, accOut);
    const int lane = tid & 63;
    const int nb = (tid >> 6) * 32;
    const int rA = lane & 15, kg = lane >> 4;
#pragma unroll
    for (int rt = 0; rt < 4; ++rt)
#pragma unroll
        for (int ct = 0; ct < 2; ++ct) {
            int col = nb + ct * 16 + rA;
#pragma unroll
            for (int i = 0; i < 4; ++i) {
                int row = rt * 16 + kg * 4 + i;
                atomicAdd(&aggr[(size_t)rd[row] * Hh + col], accOut[rt][ct][i]);
            }
        }
}

// ---------------- node update MLP -> bf16 h ----------------
__global__ __launch_bounds__(256) void k_node(
    const unsigned short* __restrict__ hb, const float* __restrict__ aggr,
    const unsigned short* __restrict__ Wa, const float* __restrict__ ba,
    const unsigned short* __restrict__ Wb, const float* __restrict__ bb,
    unsigned short* __restrict__ hnew)
{
    __shared__ unsigned short A1[64 * 264];
    const int m0 = blockIdx.x * 64;
    const int tid = threadIdx.x;
    for (int i = tid; i < 64 * 16; i += 256) {
        int row = i >> 4, ch = i & 15;
        int n = min(m0 + row, Nn - 1);
        *(uint4*)&A1[row * 264 + ch * 8] =
            *(const uint4*)&hb[(size_t)n * Hh + ch * 8];
    }
    for (int i = tid; i < 64 * 32; i += 256) {
        int row = i >> 5, c = i & 31;
        int n = min(m0 + row, Nn - 1);
        float4 v = *(const float4*)&aggr[(size_t)n * Hh + c * 4];
        ushort4 o;
        o.x = f2bf(v.x); o.y = f2bf(v.y); o.z = f2bf(v.z); o.w = f2bf(v.w);
        *(ushort4*)&A1[row * 264 + 128 + c * 4] = o;
    }
    __syncthreads();
    float accOut[4][2][4];
    mfma_mlp2<256, 264>(A1, A1, Wa, ba, Wb, bb, accOut);
    const int lane = tid & 63;
    const int nb = (tid >> 6) * 32;
    const int rA = lane & 15, kg = lane >> 4;
#pragma unroll
    for (int rt = 0; rt < 4; ++rt)
#pragma unroll
        for (int ct = 0; ct < 2; ++ct) {
            int col = nb + ct * 16 + rA;
#pragma unroll
            for (int i = 0; i < 4; ++i) {
                int row = rt * 16 + kg * 4 + i;
                int n = m0 + row;
                if (n < Nn)
                    hnew[(size_t)n * Hh + col] = f2bf(accOut[rt][ct][i]);
            }
        }
}

// ---------------- global mean pool (atomic) ----------------
__global__ void k_pool(const unsigned short* __restrict__ hb, const int* __restrict__ batch,
                       float* __restrict__ pooled, float* __restrict__ cntg) {
    int i = blockIdx.x * blockDim.x + threadIdx.x;
    if (i >= Nn * 32) return;
    int n = i >> 5;
    int cc = (i & 31) * 4;
    int b = batch[n];
    ushort4 v = *(const ushort4*)&hb[(size_t)n * Hh + cc];
    atomicAdd(&pooled[b * Hh + cc + 0], bf2f(v.x));
    atomicAdd(&pooled[b * Hh + cc + 1], bf2f(v.y));
    atomicAdd(&pooled[b * Hh + cc + 2], bf2f(v.z));
    atomicAdd(&pooled[b * Hh + cc + 3], bf2f(v.w));
    if (cc == 0) atomicAdd(&cntg[b], 1.f);
}

// ---------------- final per-graph MLP ----------------
__global__ __launch_bounds__(128) void k_final(
    const float* __restrict__ pooled, const float* __restrict__ cntg,
    const float* __restrict__ Woa, const float* __restrict__ boa,
    const float* __restrict__ Wob, const float* __restrict__ bob,
    float* __restrict__ out)
{
    __shared__ float p[128];
    __shared__ float t[128];
    __shared__ float red[128];
    const int g = blockIdx.x;
    const int j = threadIdx.x;
    float c = fmaxf(cntg[g], 1.f);
    p[j] = fmaxf(pooled[g * Hh + j] / c, 0.f);
    __syncthreads();
    float acc = boa[j];
    for (int d = 0; d < Hh; ++d) acc = fmaf(p[d], Woa[d * Hh + j], acc);
    t[j] = fmaxf(acc, 0.f);
    __syncthreads();
    red[j] = t[j] * Wob[j];
    __syncthreads();
    for (int s = 64; s > 0; s >>= 1) {
        if (j < s) red[j] += red[j + s];
        __syncthreads();
    }
    if (j == 0) out[g] = red[0] + bob[0];
}

extern "C" void kernel_launch(void* const* d_in, const int* in_sizes, int n_in,
                              void* d_out, int out_size, void* d_ws, size_t ws_size,
                              hipStream_t stream) {
    const float* x     = (const float*)d_in[0];
    const float* rbf   = (const float*)d_in[1];
    const float* cbf   = (const float*)d_in[2];
    const float* sbf   = (const float*)d_in[3];
    const int*   eidx  = (const int*)d_in[4];
    const int*   l_idx = (const int*)d_in[5];
    const int*   k_idx = (const int*)d_in[6];
    const int*   batch = (const int*)d_in[7];
    const float* W_e1a = (const float*)d_in[8];
    const float* b_e1a = (const float*)d_in[9];
    const float* W_e1b = (const float*)d_in[10];
    const float* b_e1b = (const float*)d_in[11];
    const float* W_e2a = (const float*)d_in[12];
    const float* b_e2a = (const float*)d_in[13];
    const float* W_e2b = (const float*)d_in[14];
    const float* b_e2b = (const float*)d_in[15];
    const float* W_na  = (const float*)d_in[16];
    const float* b_na  = (const float*)d_in[17];
    const float* W_nb  = (const float*)d_in[18];
    const float* b_nb  = (const float*)d_in[19];
    const float* W_oa  = (const float*)d_in[20];
    const float* b_oa  = (const float*)d_in[21];
    const float* W_ob  = (const float*)d_in[22];
    const float* b_ob  = (const float*)d_in[23];

    const int* src = eidx;
    const int* dst = eidx + Ee;

    const size_t NHf = (size_t)Nn * Hh * sizeof(float);
    const size_t NHb = (size_t)Nn * Hh * sizeof(unsigned short);
    char* w = (char*)d_ws;
    unsigned short* hb0 = (unsigned short*)w; w += NHb;
    unsigned short* hb1 = (unsigned short*)w; w += NHb;
    float* agg2   = (float*)w; w += NHf;
    float* aggr   = (float*)w; w += NHf;
    float* pooled = (float*)w; w += (size_t)Gg * Hh * sizeof(float);
    float* cntg   = (float*)w; w += (size_t)Gg * sizeof(float);
    int*   qlist  = (int*)w;   w += (size_t)Qq * sizeof(int);
    int*   qcnt   = (int*)w;   w += 16;
    unsigned short* wbuf = (unsigned short*)w;   // 3 layers x 135168 bf16

    // per-layer bf16 transposed weight layout
    const size_t LSTRIDE = 135168;
    const size_t oWq1 = 0, oWq2 = 20480, oWe1 = 36864, oWe2 = 69632, oWn1 = 86016, oWn2 = 118784;

    hipMemsetAsync(qcnt, 0, sizeof(int), stream);
    k_compact<<<(Qq + 255) / 256, 256, 0, stream>>>(k_idx, qlist, qcnt);
    k_h0<<<(Nn * Hh + 255) / 256, 256, 0, stream>>>(x, hb0);

    for (int p = 0; p < 3; ++p) {
        unsigned short* base = wbuf + p * LSTRIDE;
        k_wt<<<(128 * 160 + 255) / 256, 256, 0, stream>>>(W_e1a + (size_t)p * 146 * 128, base + oWq1, 146, 160);
        k_wt<<<(128 * 128 + 255) / 256, 256, 0, stream>>>(W_e1b + (size_t)p * 128 * 128, base + oWq2, 128, 128);
        k_wt<<<(128 * 256 + 255) / 256, 256, 0, stream>>>(W_e2a + (size_t)p * 256 * 128, base + oWe1, 256, 256);
        k_wt<<<(128 * 128 + 255) / 256, 256, 0, stream>>>(W_e2b + (size_t)p * 128 * 128, base + oWe2, 128, 128);
        k_wt<<<(128 * 256 + 255) / 256, 256, 0, stream>>>(W_na  + (size_t)p * 256 * 128, base + oWn1, 256, 256);
        k_wt<<<(128 * 128 + 255) / 256, 256, 0, stream>>>(W_nb  + (size_t)p * 128 * 128, base + oWn2, 128, 128);
    }

    unsigned short* bufs[2] = { hb0, hb1 };
    int cur = 0;
    for (int p = 0; p < 3; ++p) {
        unsigned short* base = wbuf + p * LSTRIDE;
        hipMemsetAsync(agg2, 0, NHf, stream);
        hipMemsetAsync(aggr, 0, NHf, stream);
        k_quad<<<(Qq + 63) / 64, 256, 0, stream>>>(bufs[cur], rbf, cbf, sbf, l_idx, k_idx,
            qlist, qcnt,
            base + oWq1, b_e1a + (size_t)p * 128,
            base + oWq2, b_e1b + (size_t)p * 128, agg2);
        k_edge<<<Ee / 64, 256, 0, stream>>>(bufs[cur], agg2, src, dst,
            base + oWe1, b_e2a + (size_t)p * 128,
            base + oWe2, b_e2b + (size_t)p * 128, aggr);
        k_node<<<(Nn + 63) / 64, 256, 0, stream>>>(bufs[cur], aggr,
            base + oWn1, b_na + (size_t)p * 128,
            base + oWn2, b_nb + (size_t)p * 128, bufs[cur ^ 1]);
        cur ^= 1;
    }
    hipMemsetAsync(pooled, 0, (size_t)Gg * Hh * sizeof(float), stream);
    hipMemsetAsync(cntg, 0, (size_t)Gg * sizeof(float), stream);
    k_pool<<<(Nn * 32 + 255) / 256, 256, 0, stream>>>(bufs[cur], batch, pooled, cntg);
    k_final<<<Gg, 128, 0, stream>>>(pooled, cntg, W_oa, b_oa, W_ob, b_ob, (float*)d_out);
}

// Round 3
// 1662.208 us; speedup vs baseline: 3.4902x; 1.4646x over previous
//
#include <hip/hip_runtime.h>

constexpr int Nn = 50000;
constexpr int Ee = 800000;
constexpr int Qq = 2000000;
constexpr int Gg = 64;
constexpr int Hh = 128;

typedef short bf16x8 __attribute__((ext_vector_type(8)));
typedef float f32x4  __attribute__((ext_vector_type(4)));

__device__ __forceinline__ unsigned short f2bf(float f) {
    unsigned u = __builtin_bit_cast(unsigned, f);
    u += 0x7FFFu + ((u >> 16) & 1u);
    return (unsigned short)(u >> 16);
}
__device__ __forceinline__ float bf2f(unsigned short s) {
    unsigned u = ((unsigned)s) << 16;
    return __builtin_bit_cast(float, u);
}

// ---------------- compact useful quadruplets (k_idx < Nn) ----------------
// Block-local LDS scan, ONE atomic per 4096 elements (was: 1 per wave on a
// single counter -> heavy same-address serialization).
__global__ __launch_bounds__(256) void k_compact(const int* __restrict__ kidx,
                                                 int* __restrict__ list,
                                                 int* __restrict__ cnt) {
    __shared__ int s[256];
    __shared__ int sbase;
    constexpr int EPT = 16;
    const int base = blockIdx.x * 256 * EPT;
    const int tid = threadIdx.x;
    int c = 0;
#pragma unroll
    for (int i = 0; i < EPT; ++i) {
        int q = base + i * 256 + tid;
        c += (q < Qq && kidx[q] < Nn) ? 1 : 0;
    }
    s[tid] = c;
    __syncthreads();
    for (int off = 1; off < 256; off <<= 1) {
        int v = (tid >= off) ? s[tid - off] : 0;
        __syncthreads();
        s[tid] += v;
        __syncthreads();
    }
    if (tid == 255) sbase = atomicAdd(cnt, s[255]);
    int mybase = s[tid] - c;
    __syncthreads();
    int pos = sbase + mybase;
#pragma unroll
    for (int i = 0; i < EPT; ++i) {
        int q = base + i * 256 + tid;
        if (q < Qq && kidx[q] < Nn) list[pos++] = q;
    }
}

// ---------------- weight transpose+pad to bf16 [128][Kp] (k-contiguous) ----------------
__global__ void k_wt(const float* __restrict__ in, unsigned short* __restrict__ out,
                     int K, int Kp) {
    int idx = blockIdx.x * blockDim.x + threadIdx.x;
    if (idx >= 128 * Kp) return;
    int n = idx / Kp, k = idx - n * Kp;
    out[idx] = (k < K) ? f2bf(in[(size_t)k * 128 + n]) : (unsigned short)0;
}

// ---------------- x -> bf16 h0 ----------------
__global__ void k_h0(const float* __restrict__ x, unsigned short* __restrict__ hb) {
    int idx = blockIdx.x * blockDim.x + threadIdx.x;
    if (idx < Nn * Hh) hb[idx] = f2bf(x[idx]);
}

// ---------------- fused 2-layer MFMA MLP on a 64-row tile ----------------
template<int K1P, int SA1>
__device__ __forceinline__ void mfma_mlp2(
    const unsigned short* A1, unsigned short* A2,
    const unsigned short* __restrict__ Wa, const float* __restrict__ ba,
    const unsigned short* __restrict__ Wb, const float* __restrict__ bb,
    float accOut[4][2][4])
{
    const int tid  = threadIdx.x;
    const int lane = tid & 63;
    const int wid  = tid >> 6;
    const int nb   = wid * 32;
    const int rA   = lane & 15;
    const int kg   = lane >> 4;     // 0..3

    f32x4 acc[4][2];
#pragma unroll
    for (int rt = 0; rt < 4; ++rt)
#pragma unroll
        for (int ct = 0; ct < 2; ++ct)
            acc[rt][ct] = (f32x4){0.f, 0.f, 0.f, 0.f};

#pragma unroll
    for (int ks = 0; ks < K1P / 32; ++ks) {
        const int k0 = ks * 32 + kg * 8;
        bf16x8 b0 = *(const bf16x8*)&Wa[(size_t)(nb + rA) * K1P + k0];
        bf16x8 b1 = *(const bf16x8*)&Wa[(size_t)(nb + 16 + rA) * K1P + k0];
#pragma unroll
        for (int rt = 0; rt < 4; ++rt) {
            bf16x8 a = *(const bf16x8*)&A1[(rt * 16 + rA) * SA1 + k0];
            acc[rt][0] = __builtin_amdgcn_mfma_f32_16x16x32_bf16(a, b0, acc[rt][0], 0, 0, 0);
            acc[rt][1] = __builtin_amdgcn_mfma_f32_16x16x32_bf16(a, b1, acc[rt][1], 0, 0, 0);
        }
    }
    __syncthreads();            // all A1 reads done before A2 overwrite
#pragma unroll
    for (int rt = 0; rt < 4; ++rt)
#pragma unroll
        for (int ct = 0; ct < 2; ++ct) {
            int col = nb + ct * 16 + rA;
            float bias = ba[col];
#pragma unroll
            for (int i = 0; i < 4; ++i) {
                int row = rt * 16 + kg * 4 + i;
                A2[row * 136 + col] = f2bf(fmaxf(acc[rt][ct][i] + bias, 0.f));
            }
        }
    __syncthreads();

    f32x4 acc2[4][2];
#pragma unroll
    for (int rt = 0; rt < 4; ++rt)
#pragma unroll
        for (int ct = 0; ct < 2; ++ct)
            acc2[rt][ct] = (f32x4){0.f, 0.f, 0.f, 0.f};

#pragma unroll
    for (int ks = 0; ks < 4; ++ks) {
        const int k0 = ks * 32 + kg * 8;
        bf16x8 b0 = *(const bf16x8*)&Wb[(size_t)(nb + rA) * 128 + k0];
        bf16x8 b1 = *(const bf16x8*)&Wb[(size_t)(nb + 16 + rA) * 128 + k0];
#pragma unroll
        for (int rt = 0; rt < 4; ++rt) {
            bf16x8 a = *(const bf16x8*)&A2[(rt * 16 + rA) * 136 + k0];
            acc2[rt][0] = __builtin_amdgcn_mfma_f32_16x16x32_bf16(a, b0, acc2[rt][0], 0, 0, 0);
            acc2[rt][1] = __builtin_amdgcn_mfma_f32_16x16x32_bf16(a, b1, acc2[rt][1], 0, 0, 0);
        }
    }
#pragma unroll
    for (int rt = 0; rt < 4; ++rt)
#pragma unroll
        for (int ct = 0; ct < 2; ++ct) {
            int col = nb + ct * 16 + rA;
            float bias = bb[col];
#pragma unroll
            for (int i = 0; i < 4; ++i)
                accOut[rt][ct][i] = acc2[rt][ct][i] + bias;
        }
}

// ---------------- quadruplet message MLP + scatter into agg2[k_idx] ----------------
__global__ __launch_bounds__(256) void k_quad(
    const unsigned short* __restrict__ hb,
    const float* __restrict__ rbf, const float* __restrict__ cbf, const float* __restrict__ sbf,
    const int* __restrict__ l_idx, const int* __restrict__ k_idx,
    const int* __restrict__ list, const int* __restrict__ cnt,
    const unsigned short* __restrict__ Wa, const float* __restrict__ ba,
    const unsigned short* __restrict__ Wb, const float* __restrict__ bb,
    float* __restrict__ agg2)
{
    __shared__ unsigned short A1[64 * 168];
    __shared__ int rqi[64], rli[64], rki[64];
    const int Qu = *cnt;
    const int tid = threadIdx.x;
    for (int m0 = blockIdx.x * 64; m0 < Qu; m0 += gridDim.x * 64) {
        if (tid < 64) {
            int m = m0 + tid;
            int q = list[min(m, Qu - 1)];
            rqi[tid] = q; rli[tid] = l_idx[q]; rki[tid] = k_idx[q];
        }
        __syncthreads();
        for (int i = tid; i < 64 * 16; i += 256) {
            int row = i >> 4, ch = i & 15;
            *(uint4*)&A1[row * 168 + ch * 8] =
                *(const uint4*)&hb[(size_t)rli[row] * Hh + ch * 8];
        }
        for (int i = tid; i < 64 * 32; i += 256) {
            int row = i >> 5, c = i & 31;
            int q = rqi[row], ki = rki[row];
            float v = 0.f;
            if (c < 6)       v = rbf[(size_t)ki * 6 + c];
            else if (c < 12) v = cbf[(size_t)q * 6 + (c - 6)];
            else if (c < 18) v = sbf[(size_t)q * 6 + (c - 12)];
            A1[row * 168 + 128 + c] = f2bf(v);
        }
        __syncthreads();
        float accOut[4][2][4];
        mfma_mlp2<160, 168>(A1, A1, Wa, ba, Wb, bb, accOut);
        const int lane = tid & 63;
        const int nb = (tid >> 6) * 32;
        const int rA = lane & 15, kg = lane >> 4;
#pragma unroll
        for (int rt = 0; rt < 4; ++rt)
#pragma unroll
            for (int ct = 0; ct < 2; ++ct) {
                int col = nb + ct * 16 + rA;
#pragma unroll
                for (int i = 0; i < 4; ++i) {
                    int row = rt * 16 + kg * 4 + i;
                    if (m0 + row < Qu)
                        atomicAdd(&agg2[(size_t)rki[row] * Hh + col], accOut[rt][ct][i]);
                }
            }
        __syncthreads();   // LDS reuse across tile iterations
    }
}

// ---------------- edge MLP + scatter into aggr[dst] ----------------
__global__ __launch_bounds__(256) void k_edge(
    const unsigned short* __restrict__ hb, const float* __restrict__ agg2,
    const int* __restrict__ src, const int* __restrict__ dst,
    const unsigned short* __restrict__ Wa, const float* __restrict__ ba,
    const unsigned short* __restrict__ Wb, const float* __restrict__ bb,
    float* __restrict__ aggr)
{
    __shared__ unsigned short A1[64 * 264];
    __shared__ int rs[64], rd[64];
    const int m0 = blockIdx.x * 64;         // Ee % 64 == 0
    const int tid = threadIdx.x;
    if (tid < 64) { rs[tid] = src[m0 + tid]; rd[tid] = dst[m0 + tid]; }
    __syncthreads();
    for (int i = tid; i < 64 * 16; i += 256) {
        int row = i >> 4, ch = i & 15;
        *(uint4*)&A1[row * 264 + ch * 8] =
            *(const uint4*)&hb[(size_t)rs[row] * Hh + ch * 8];
    }
    for (int i = tid; i < 64 * 32; i += 256) {
        int row = i >> 5, c = i & 31;
        float4 v = *(const float4*)&agg2[(size_t)rd[row] * Hh + c * 4];
        ushort4 o;
        o.x = f2bf(v.x); o.y = f2bf(v.y); o.z = f2bf(v.z); o.w = f2bf(v.w);
        *(ushort4*)&A1[row * 264 + 128 + c * 4] = o;
    }
    __syncthreads();
    float accOut[4][2][4];
    mfma_mlp2<256, 264>(A1, A1, Wa, ba, Wb, bb, accOut);
    const int lane = tid & 63;
    const int nb = (tid >> 6) * 32;
    const int rA = lane & 15, kg = lane >> 4;
#pragma unroll
    for (int rt = 0; rt < 4; ++rt)
#pragma unroll
        for (int ct = 0; ct < 2; ++ct) {
            int col = nb + ct * 16 + rA;
#pragma unroll
            for (int i = 0; i < 4; ++i) {
                int row = rt * 16 + kg * 4 + i;
                atomicAdd(&aggr[(size_t)rd[row] * Hh + col], accOut[rt][ct][i]);
            }
        }
}

// ---------------- node update MLP -> bf16 h ----------------
__global__ __launch_bounds__(256) void k_node(
    const unsigned short* __restrict__ hb, const float* __restrict__ aggr,
    const unsigned short* __restrict__ Wa, const float* __restrict__ ba,
    const unsigned short* __restrict__ Wb, const float* __restrict__ bb,
    unsigned short* __restrict__ hnew)
{
    __shared__ unsigned short A1[64 * 264];
    const int m0 = blockIdx.x * 64;
    const int tid = threadIdx.x;
    for (int i = tid; i < 64 * 16; i += 256) {
        int row = i >> 4, ch = i & 15;
        int n = min(m0 + row, Nn - 1);
        *(uint4*)&A1[row * 264 + ch * 8] =
            *(const uint4*)&hb[(size_t)n * Hh + ch * 8];
    }
    for (int i = tid; i < 64 * 32; i += 256) {
        int row = i >> 5, c = i & 31;
        int n = min(m0 + row, Nn - 1);
        float4 v = *(const float4*)&aggr[(size_t)n * Hh + c * 4];
        ushort4 o;
        o.x = f2bf(v.x); o.y = f2bf(v.y); o.z = f2bf(v.z); o.w = f2bf(v.w);
        *(ushort4*)&A1[row * 264 + 128 + c * 4] = o;
    }
    __syncthreads();
    float accOut[4][2][4];
    mfma_mlp2<256, 264>(A1, A1, Wa, ba, Wb, bb, accOut);
    const int lane = tid & 63;
    const int nb = (tid >> 6) * 32;
    const int rA = lane & 15, kg = lane >> 4;
#pragma unroll
    for (int rt = 0; rt < 4; ++rt)
#pragma unroll
        for (int ct = 0; ct < 2; ++ct) {
            int col = nb + ct * 16 + rA;
#pragma unroll
            for (int i = 0; i < 4; ++i) {
                int row = rt * 16 + kg * 4 + i;
                int n = m0 + row;
                if (n < Nn)
                    hnew[(size_t)n * Hh + col] = f2bf(accOut[rt][ct][i]);
            }
        }
}

// ---------------- global mean pool: run-length segmented reduction ----------------
// batch is SORTED -> each 196-node chunk spans ~1-2 graphs; accumulate per-thread
// partials in registers, one atomic per (segment x col). ~51K atomics total
// (was 6.4M with 781-way same-address contention).
__global__ __launch_bounds__(256) void k_pool(const unsigned short* __restrict__ hb,
                                              const int* __restrict__ batch,
                                              float* __restrict__ pooled,
                                              float* __restrict__ cntg) {
    __shared__ int bseg[200];
    constexpr int CH = 196;
    const int start = blockIdx.x * CH;
    const int end = min(start + CH, Nn);
    if (start >= end) return;
    const int tid = threadIdx.x;
    for (int i = tid; i < end - start; i += 256) bseg[i] = batch[start + i];
    __syncthreads();
    const int j = tid & 127;
    const int rh = tid >> 7;
    float acc = 0.f, cacc = 0.f;
    int cur = -1;
    for (int n = start + rh; n < end; n += 2) {
        int g = bseg[n - start];
        if (g != cur) {
            if (cur >= 0) {
                atomicAdd(&pooled[cur * Hh + j], acc);
                if (j == 0) atomicAdd(&cntg[cur], cacc);
            }
            cur = g; acc = 0.f; cacc = 0.f;
        }
        acc += bf2f(hb[(size_t)n * Hh + j]);
        cacc += 1.f;
    }
    if (cur >= 0) {
        atomicAdd(&pooled[cur * Hh + j], acc);
        if (j == 0) atomicAdd(&cntg[cur], cacc);
    }
}

// ---------------- final per-graph MLP ----------------
__global__ __launch_bounds__(128) void k_final(
    const float* __restrict__ pooled, const float* __restrict__ cntg,
    const float* __restrict__ Woa, const float* __restrict__ boa,
    const float* __restrict__ Wob, const float* __restrict__ bob,
    float* __restrict__ out)
{
    __shared__ float p[128];
    __shared__ float t[128];
    __shared__ float red[128];
    const int g = blockIdx.x;
    const int j = threadIdx.x;
    float c = fmaxf(cntg[g], 1.f);
    p[j] = fmaxf(pooled[g * Hh + j] / c, 0.f);
    __syncthreads();
    float acc = boa[j];
    for (int d = 0; d < Hh; ++d) acc = fmaf(p[d], Woa[d * Hh + j], acc);
    t[j] = fmaxf(acc, 0.f);
    __syncthreads();
    red[j] = t[j] * Wob[j];
    __syncthreads();
    for (int s = 64; s > 0; s >>= 1) {
        if (j < s) red[j] += red[j + s];
        __syncthreads();
    }
    if (j == 0) out[g] = red[0] + bob[0];
}

extern "C" void kernel_launch(void* const* d_in, const int* in_sizes, int n_in,
                              void* d_out, int out_size, void* d_ws, size_t ws_size,
                              hipStream_t stream) {
    const float* x     = (const float*)d_in[0];
    const float* rbf   = (const float*)d_in[1];
    const float* cbf   = (const float*)d_in[2];
    const float* sbf   = (const float*)d_in[3];
    const int*   eidx  = (const int*)d_in[4];
    const int*   l_idx = (const int*)d_in[5];
    const int*   k_idx = (const int*)d_in[6];
    const int*   batch = (const int*)d_in[7];
    const float* W_e1a = (const float*)d_in[8];
    const float* b_e1a = (const float*)d_in[9];
    const float* W_e1b = (const float*)d_in[10];
    const float* b_e1b = (const float*)d_in[11];
    const float* W_e2a = (const float*)d_in[12];
    const float* b_e2a = (const float*)d_in[13];
    const float* W_e2b = (const float*)d_in[14];
    const float* b_e2b = (const float*)d_in[15];
    const float* W_na  = (const float*)d_in[16];
    const float* b_na  = (const float*)d_in[17];
    const float* W_nb  = (const float*)d_in[18];
    const float* b_nb  = (const float*)d_in[19];
    const float* W_oa  = (const float*)d_in[20];
    const float* b_oa  = (const float*)d_in[21];
    const float* W_ob  = (const float*)d_in[22];
    const float* b_ob  = (const float*)d_in[23];

    const int* src = eidx;
    const int* dst = eidx + Ee;

    const size_t NHf = (size_t)Nn * Hh * sizeof(float);
    const size_t NHb = (size_t)Nn * Hh * sizeof(unsigned short);
    char* w = (char*)d_ws;
    unsigned short* hb0 = (unsigned short*)w; w += NHb;
    unsigned short* hb1 = (unsigned short*)w; w += NHb;
    float* agg2   = (float*)w; w += NHf;
    float* aggr   = (float*)w; w += NHf;
    float* pooled = (float*)w; w += (size_t)Gg * Hh * sizeof(float);
    float* cntg   = (float*)w; w += (size_t)Gg * sizeof(float);
    int*   qlist  = (int*)w;   w += (size_t)Qq * sizeof(int);
    int*   qcnt   = (int*)w;   w += 16;
    unsigned short* wbuf = (unsigned short*)w;   // 3 layers x 135168 bf16

    const size_t LSTRIDE = 135168;
    const size_t oWq1 = 0, oWq2 = 20480, oWe1 = 36864, oWe2 = 69632, oWn1 = 86016, oWn2 = 118784;

    hipMemsetAsync(qcnt, 0, sizeof(int), stream);
    k_compact<<<(Qq + 4095) / 4096, 256, 0, stream>>>(k_idx, qlist, qcnt);
    k_h0<<<(Nn * Hh + 255) / 256, 256, 0, stream>>>(x, hb0);

    for (int p = 0; p < 3; ++p) {
        unsigned short* base = wbuf + p * LSTRIDE;
        k_wt<<<(128 * 160 + 255) / 256, 256, 0, stream>>>(W_e1a + (size_t)p * 146 * 128, base + oWq1, 146, 160);
        k_wt<<<(128 * 128 + 255) / 256, 256, 0, stream>>>(W_e1b + (size_t)p * 128 * 128, base + oWq2, 128, 128);
        k_wt<<<(128 * 256 + 255) / 256, 256, 0, stream>>>(W_e2a + (size_t)p * 256 * 128, base + oWe1, 256, 256);
        k_wt<<<(128 * 128 + 255) / 256, 256, 0, stream>>>(W_e2b + (size_t)p * 128 * 128, base + oWe2, 128, 128);
        k_wt<<<(128 * 256 + 255) / 256, 256, 0, stream>>>(W_na  + (size_t)p * 256 * 128, base + oWn1, 256, 256);
        k_wt<<<(128 * 128 + 255) / 256, 256, 0, stream>>>(W_nb  + (size_t)p * 128 * 128, base + oWn2, 128, 128);
    }

    unsigned short* bufs[2] = { hb0, hb1 };
    int cur = 0;
    for (int p = 0; p < 3; ++p) {
        unsigned short* base = wbuf + p * LSTRIDE;
        hipMemsetAsync(agg2, 0, NHf, stream);
        hipMemsetAsync(aggr, 0, NHf, stream);
        k_quad<<<2048, 256, 0, stream>>>(bufs[cur], rbf, cbf, sbf, l_idx, k_idx,
            qlist, qcnt,
            base + oWq1, b_e1a + (size_t)p * 128,
            base + oWq2, b_e1b + (size_t)p * 128, agg2);
        k_edge<<<Ee / 64, 256, 0, stream>>>(bufs[cur], agg2, src, dst,
            base + oWe1, b_e2a + (size_t)p * 128,
            base + oWe2, b_e2b + (size_t)p * 128, aggr);
        k_node<<<(Nn + 63) / 64, 256, 0, stream>>>(bufs[cur], aggr,
            base + oWn1, b_na + (size_t)p * 128,
            base + oWn2, b_nb + (size_t)p * 128, bufs[cur ^ 1]);
        cur ^= 1;
    }
    hipMemsetAsync(pooled, 0, (size_t)Gg * Hh * sizeof(float), stream);
    hipMemsetAsync(cntg, 0, (size_t)Gg * sizeof(float), stream);
    k_pool<<<(Nn + 195) / 196, 256, 0, stream>>>(bufs[cur], batch, pooled, cntg);
    k_final<<<Gg, 128, 0, stream>>>(pooled, cntg, W_oa, b_oa, W_ob, b_ob, (float*)d_out);
}

// Round 4
// 1382.914 us; speedup vs baseline: 4.1951x; 1.2020x over previous
//
#include <hip/hip_runtime.h>

constexpr int Nn = 50000;
constexpr int Ee = 800000;
constexpr int Qq = 2000000;
constexpr int Gg = 64;
constexpr int Hh = 128;

typedef short bf16x8 __attribute__((ext_vector_type(8)));
typedef float f32x4  __attribute__((ext_vector_type(4)));

__device__ __forceinline__ unsigned short f2bf(float f) {
    unsigned u = __builtin_bit_cast(unsigned, f);
    u += 0x7FFFu + ((u >> 16) & 1u);
    return (unsigned short)(u >> 16);
}
__device__ __forceinline__ float bf2f(unsigned short s) {
    unsigned u = ((unsigned)s) << 16;
    return __builtin_bit_cast(float, u);
}

// ---------------- counting sort: histogram ----------------
__global__ void k_hist(const int* __restrict__ idx, int n, int limit,
                       int* __restrict__ hist) {
    int i = blockIdx.x * blockDim.x + threadIdx.x;
    if (i < n) { int v = idx[i]; if (v < limit) atomicAdd(&hist[v], 1); }
}

// ---------------- counting sort: single-block exclusive scan over Nn bins ----------------
__global__ __launch_bounds__(1024) void k_scan(const int* __restrict__ hist,
                                               int* __restrict__ cursor,
                                               int* __restrict__ total) {
    __shared__ int s[1024];
    const int tid = threadIdx.x;
    const int per = (Nn + 1023) / 1024;
    int start = tid * per, end = min(start + per, Nn);
    int sum = 0;
    for (int i = start; i < end; ++i) sum += hist[i];
    s[tid] = sum;
    __syncthreads();
    for (int off = 1; off < 1024; off <<= 1) {
        int v = (tid >= off) ? s[tid - off] : 0;
        __syncthreads();
        s[tid] += v;
        __syncthreads();
    }
    int base = s[tid] - sum;
    for (int i = start; i < end; ++i) {
        cursor[i] = base;
        base += hist[i];
    }
    if (tid == 1023 && total) *total = s[1023];
}

// ---------------- counting sort: scatter ----------------
__global__ void k_scatter(const int* __restrict__ idx, int n, int limit,
                          int* __restrict__ cursor, int* __restrict__ perm) {
    int i = blockIdx.x * blockDim.x + threadIdx.x;
    if (i < n) {
        int v = idx[i];
        if (v < limit) { int p = atomicAdd(&cursor[v], 1); perm[p] = i; }
    }
}

// ---------------- weight transpose+pad to bf16 [128][Kp] (k-contiguous) ----------------
__global__ void k_wt(const float* __restrict__ in, unsigned short* __restrict__ out,
                     int K, int Kp) {
    int idx = blockIdx.x * blockDim.x + threadIdx.x;
    if (idx >= 128 * Kp) return;
    int n = idx / Kp, k = idx - n * Kp;
    out[idx] = (k < K) ? f2bf(in[(size_t)k * 128 + n]) : (unsigned short)0;
}

// ---------------- x -> bf16 h0 ----------------
__global__ void k_h0(const float* __restrict__ x, unsigned short* __restrict__ hb) {
    int idx = blockIdx.x * blockDim.x + threadIdx.x;
    if (idx < Nn * Hh) hb[idx] = f2bf(x[idx]);
}

// ---------------- f32 -> bf16 convert (agg2) ----------------
__global__ void k_cvt(const float* __restrict__ in, unsigned short* __restrict__ out,
                      int n) {
    int i = blockIdx.x * blockDim.x + threadIdx.x;
    if (i * 4 < n) {
        float4 v = *(const float4*)&in[i * 4];
        ushort4 o;
        o.x = f2bf(v.x); o.y = f2bf(v.y); o.z = f2bf(v.z); o.w = f2bf(v.w);
        *(ushort4*)&out[i * 4] = o;
    }
}

// ---------------- fused 2-layer MFMA MLP on a 64-row tile ----------------
template<int K1P, int SA1>
__device__ __forceinline__ void mfma_mlp2(
    const unsigned short* A1, unsigned short* A2,
    const unsigned short* __restrict__ Wa, const float* __restrict__ ba,
    const unsigned short* __restrict__ Wb, const float* __restrict__ bb,
    float accOut[4][2][4])
{
    const int tid  = threadIdx.x;
    const int lane = tid & 63;
    const int wid  = tid >> 6;
    const int nb   = wid * 32;
    const int rA   = lane & 15;
    const int kg   = lane >> 4;     // 0..3

    f32x4 acc[4][2];
#pragma unroll
    for (int rt = 0; rt < 4; ++rt)
#pragma unroll
        for (int ct = 0; ct < 2; ++ct)
            acc[rt][ct] = (f32x4){0.f, 0.f, 0.f, 0.f};

#pragma unroll
    for (int ks = 0; ks < K1P / 32; ++ks) {
        const int k0 = ks * 32 + kg * 8;
        bf16x8 b0 = *(const bf16x8*)&Wa[(size_t)(nb + rA) * K1P + k0];
        bf16x8 b1 = *(const bf16x8*)&Wa[(size_t)(nb + 16 + rA) * K1P + k0];
#pragma unroll
        for (int rt = 0; rt < 4; ++rt) {
            bf16x8 a = *(const bf16x8*)&A1[(rt * 16 + rA) * SA1 + k0];
            acc[rt][0] = __builtin_amdgcn_mfma_f32_16x16x32_bf16(a, b0, acc[rt][0], 0, 0, 0);
            acc[rt][1] = __builtin_amdgcn_mfma_f32_16x16x32_bf16(a, b1, acc[rt][1], 0, 0, 0);
        }
    }
    __syncthreads();            // all A1 reads done before A2 overwrite
#pragma unroll
    for (int rt = 0; rt < 4; ++rt)
#pragma unroll
        for (int ct = 0; ct < 2; ++ct) {
            int col = nb + ct * 16 + rA;
            float bias = ba[col];
#pragma unroll
            for (int i = 0; i < 4; ++i) {
                int row = rt * 16 + kg * 4 + i;
                A2[row * 136 + col] = f2bf(fmaxf(acc[rt][ct][i] + bias, 0.f));
            }
        }
    __syncthreads();

    f32x4 acc2[4][2];
#pragma unroll
    for (int rt = 0; rt < 4; ++rt)
#pragma unroll
        for (int ct = 0; ct < 2; ++ct)
            acc2[rt][ct] = (f32x4){0.f, 0.f, 0.f, 0.f};

#pragma unroll
    for (int ks = 0; ks < 4; ++ks) {
        const int k0 = ks * 32 + kg * 8;
        bf16x8 b0 = *(const bf16x8*)&Wb[(size_t)(nb + rA) * 128 + k0];
        bf16x8 b1 = *(const bf16x8*)&Wb[(size_t)(nb + 16 + rA) * 128 + k0];
#pragma unroll
        for (int rt = 0; rt < 4; ++rt) {
            bf16x8 a = *(const bf16x8*)&A2[(rt * 16 + rA) * 136 + k0];
            acc2[rt][0] = __builtin_amdgcn_mfma_f32_16x16x32_bf16(a, b0, acc2[rt][0], 0, 0, 0);
            acc2[rt][1] = __builtin_amdgcn_mfma_f32_16x16x32_bf16(a, b1, acc2[rt][1], 0, 0, 0);
        }
    }
#pragma unroll
    for (int rt = 0; rt < 4; ++rt)
#pragma unroll
        for (int ct = 0; ct < 2; ++ct) {
            int col = nb + ct * 16 + rA;
            float bias = bb[col];
#pragma unroll
            for (int i = 0; i < 4; ++i)
                accOut[rt][ct][i] = acc2[rt][ct][i] + bias;
        }
}

// ---------------- quadruplet message MLP + scatter into agg2[k_idx] ----------------
// qlist is sorted by k_idx (counting sort) -> consecutive rows share targets;
// pre-combine equal-target partials in registers before the atomic.
__global__ __launch_bounds__(256) void k_quad(
    const unsigned short* __restrict__ hb,
    const float* __restrict__ rbf, const float* __restrict__ cbf, const float* __restrict__ sbf,
    const int* __restrict__ l_idx, const int* __restrict__ k_idx,
    const int* __restrict__ list, const int* __restrict__ cnt,
    const unsigned short* __restrict__ Wa, const float* __restrict__ ba,
    const unsigned short* __restrict__ Wb, const float* __restrict__ bb,
    float* __restrict__ agg2)
{
    __shared__ unsigned short A1[64 * 168];
    __shared__ int rqi[64], rli[64], rki[64];
    const int Qu = *cnt;
    const int tid = threadIdx.x;
    for (int m0 = blockIdx.x * 64; m0 < Qu; m0 += gridDim.x * 64) {
        if (tid < 64) {
            int m = m0 + tid;
            int q = list[min(m, Qu - 1)];
            rqi[tid] = q; rli[tid] = l_idx[q]; rki[tid] = k_idx[q];
        }
        __syncthreads();
        for (int i = tid; i < 64 * 16; i += 256) {
            int row = i >> 4, ch = i & 15;
            *(uint4*)&A1[row * 168 + ch * 8] =
                *(const uint4*)&hb[(size_t)rli[row] * Hh + ch * 8];
        }
        for (int i = tid; i < 64 * 32; i += 256) {
            int row = i >> 5, c = i & 31;
            int q = rqi[row], ki = rki[row];
            float v = 0.f;
            if (c < 6)       v = rbf[(size_t)ki * 6 + c];
            else if (c < 12) v = cbf[(size_t)q * 6 + (c - 6)];
            else if (c < 18) v = sbf[(size_t)q * 6 + (c - 12)];
            A1[row * 168 + 128 + c] = f2bf(v);
        }
        __syncthreads();
        float accOut[4][2][4];
        mfma_mlp2<160, 168>(A1, A1, Wa, ba, Wb, bb, accOut);
        const int lane = tid & 63;
        const int nb = (tid >> 6) * 32;
        const int rA = lane & 15, kg = lane >> 4;
#pragma unroll
        for (int rt = 0; rt < 4; ++rt)
#pragma unroll
            for (int ct = 0; ct < 2; ++ct) {
                int col = nb + ct * 16 + rA;
                float s = 0.f; int cur = -1;
#pragma unroll
                for (int i = 0; i < 4; ++i) {
                    int row = rt * 16 + kg * 4 + i;
                    int tgt = (m0 + row < Qu) ? rki[row] : -1;
                    if (tgt != cur) {
                        if (cur >= 0) atomicAdd(&agg2[(size_t)cur * Hh + col], s);
                        cur = tgt; s = 0.f;
                    }
                    s += (tgt >= 0) ? accOut[rt][ct][i] : 0.f;
                }
                if (cur >= 0) atomicAdd(&agg2[(size_t)cur * Hh + col], s);
            }
        __syncthreads();   // LDS reuse across tile iterations
    }
}

// ---------------- edge MLP over dst-sorted edges + segmented reduce into aggr ----------------
__global__ __launch_bounds__(256) void k_edge(
    const unsigned short* __restrict__ hb, const unsigned short* __restrict__ agg2b,
    const int* __restrict__ src, const int* __restrict__ dst,
    const int* __restrict__ perm,
    const unsigned short* __restrict__ Wa, const float* __restrict__ ba,
    const unsigned short* __restrict__ Wb, const float* __restrict__ bb,
    float* __restrict__ aggr)
{
    __shared__ unsigned short A1[64 * 264];   // 33792 B; reused as float[64][132]
    __shared__ int rs[64], rd[64];
    const int m0 = blockIdx.x * 64;           // Ee % 64 == 0
    const int tid = threadIdx.x;
    if (tid < 64) {
        int e = perm[m0 + tid];
        rs[tid] = src[e]; rd[tid] = dst[e];
    }
    __syncthreads();
    for (int i = tid; i < 64 * 16; i += 256) {
        int row = i >> 4, ch = i & 15;
        *(uint4*)&A1[row * 264 + ch * 8] =
            *(const uint4*)&hb[(size_t)rs[row] * Hh + ch * 8];
    }
    for (int i = tid; i < 64 * 16; i += 256) {
        int row = i >> 4, ch = i & 15;
        *(uint4*)&A1[row * 264 + 128 + ch * 8] =
            *(const uint4*)&agg2b[(size_t)rd[row] * Hh + ch * 8];
    }
    __syncthreads();
    float accOut[4][2][4];
    mfma_mlp2<256, 264>(A1, A1, Wa, ba, Wb, bb, accOut);
    const int lane = tid & 63;
    const int nb = (tid >> 6) * 32;
    const int rA = lane & 15, kg = lane >> 4;

    __syncthreads();                 // stage-2 LDS reads done; reuse A1 as f32
    float* Ared = (float*)A1;
#pragma unroll
    for (int rt = 0; rt < 4; ++rt)
#pragma unroll
        for (int ct = 0; ct < 2; ++ct) {
            int col = nb + ct * 16 + rA;
#pragma unroll
            for (int i = 0; i < 4; ++i) {
                int row = rt * 16 + kg * 4 + i;
                Ared[row * 132 + col] = accOut[rt][ct][i];
            }
        }
    __syncthreads();
    // per-column run-length reduction over dst-sorted rows: one atomic per run
    {
        const int col = tid & 127;
        const int r0 = (tid >> 7) * 32;
        float s = 0.f;
        int cur = rd[r0];
        for (int r = r0; r < r0 + 32; ++r) {
            int t = rd[r];
            if (t != cur) {
                atomicAdd(&aggr[(size_t)cur * Hh + col], s);
                cur = t; s = 0.f;
            }
            s += Ared[r * 132 + col];
        }
        atomicAdd(&aggr[(size_t)cur * Hh + col], s);
    }
}

// ---------------- node update MLP -> bf16 h ----------------
__global__ __launch_bounds__(256) void k_node(
    const unsigned short* __restrict__ hb, const float* __restrict__ aggr,
    const unsigned short* __restrict__ Wa, const float* __restrict__ ba,
    const unsigned short* __restrict__ Wb, const float* __restrict__ bb,
    unsigned short* __restrict__ hnew)
{
    __shared__ unsigned short A1[64 * 264];
    const int m0 = blockIdx.x * 64;
    const int tid = threadIdx.x;
    for (int i = tid; i < 64 * 16; i += 256) {
        int row = i >> 4, ch = i & 15;
        int n = min(m0 + row, Nn - 1);
        *(uint4*)&A1[row * 264 + ch * 8] =
            *(const uint4*)&hb[(size_t)n * Hh + ch * 8];
    }
    for (int i = tid; i < 64 * 32; i += 256) {
        int row = i >> 5, c = i & 31;
        int n = min(m0 + row, Nn - 1);
        float4 v = *(const float4*)&aggr[(size_t)n * Hh + c * 4];
        ushort4 o;
        o.x = f2bf(v.x); o.y = f2bf(v.y); o.z = f2bf(v.z); o.w = f2bf(v.w);
        *(ushort4*)&A1[row * 264 + 128 + c * 4] = o;
    }
    __syncthreads();
    float accOut[4][2][4];
    mfma_mlp2<256, 264>(A1, A1, Wa, ba, Wb, bb, accOut);
    const int lane = tid & 63;
    const int nb = (tid >> 6) * 32;
    const int rA = lane & 15, kg = lane >> 4;
#pragma unroll
    for (int rt = 0; rt < 4; ++rt)
#pragma unroll
        for (int ct = 0; ct < 2; ++ct) {
            int col = nb + ct * 16 + rA;
#pragma unroll
            for (int i = 0; i < 4; ++i) {
                int row = rt * 16 + kg * 4 + i;
                int n = m0 + row;
                if (n < Nn)
                    hnew[(size_t)n * Hh + col] = f2bf(accOut[rt][ct][i]);
            }
        }
}

// ---------------- global mean pool: run-length segmented reduction ----------------
__global__ __launch_bounds__(256) void k_pool(const unsigned short* __restrict__ hb,
                                              const int* __restrict__ batch,
                                              float* __restrict__ pooled,
                                              float* __restrict__ cntg) {
    __shared__ int bseg[200];
    constexpr int CH = 196;
    const int start = blockIdx.x * CH;
    const int end = min(start + CH, Nn);
    if (start >= end) return;
    const int tid = threadIdx.x;
    for (int i = tid; i < end - start; i += 256) bseg[i] = batch[start + i];
    __syncthreads();
    const int j = tid & 127;
    const int rh = tid >> 7;
    float acc = 0.f, cacc = 0.f;
    int cur = -1;
    for (int n = start + rh; n < end; n += 2) {
        int g = bseg[n - start];
        if (g != cur) {
            if (cur >= 0) {
                atomicAdd(&pooled[cur * Hh + j], acc);
                if (j == 0) atomicAdd(&cntg[cur], cacc);
            }
            cur = g; acc = 0.f; cacc = 0.f;
        }
        acc += bf2f(hb[(size_t)n * Hh + j]);
        cacc += 1.f;
    }
    if (cur >= 0) {
        atomicAdd(&pooled[cur * Hh + j], acc);
        if (j == 0) atomicAdd(&cntg[cur], cacc);
    }
}

// ---------------- final per-graph MLP ----------------
__global__ __launch_bounds__(128) void k_final(
    const float* __restrict__ pooled, const float* __restrict__ cntg,
    const float* __restrict__ Woa, const float* __restrict__ boa,
    const float* __restrict__ Wob, const float* __restrict__ bob,
    float* __restrict__ out)
{
    __shared__ float p[128];
    __shared__ float t[128];
    __shared__ float red[128];
    const int g = blockIdx.x;
    const int j = threadIdx.x;
    float c = fmaxf(cntg[g], 1.f);
    p[j] = fmaxf(pooled[g * Hh + j] / c, 0.f);
    __syncthreads();
    float acc = boa[j];
    for (int d = 0; d < Hh; ++d) acc = fmaf(p[d], Woa[d * Hh + j], acc);
    t[j] = fmaxf(acc, 0.f);
    __syncthreads();
    red[j] = t[j] * Wob[j];
    __syncthreads();
    for (int s = 64; s > 0; s >>= 1) {
        if (j < s) red[j] += red[j + s];
        __syncthreads();
    }
    if (j == 0) out[g] = red[0] + bob[0];
}

extern "C" void kernel_launch(void* const* d_in, const int* in_sizes, int n_in,
                              void* d_out, int out_size, void* d_ws, size_t ws_size,
                              hipStream_t stream) {
    const float* x     = (const float*)d_in[0];
    const float* rbf   = (const float*)d_in[1];
    const float* cbf   = (const float*)d_in[2];
    const float* sbf   = (const float*)d_in[3];
    const int*   eidx  = (const int*)d_in[4];
    const int*   l_idx = (const int*)d_in[5];
    const int*   k_idx = (const int*)d_in[6];
    const int*   batch = (const int*)d_in[7];
    const float* W_e1a = (const float*)d_in[8];
    const float* b_e1a = (const float*)d_in[9];
    const float* W_e1b = (const float*)d_in[10];
    const float* b_e1b = (const float*)d_in[11];
    const float* W_e2a = (const float*)d_in[12];
    const float* b_e2a = (const float*)d_in[13];
    const float* W_e2b = (const float*)d_in[14];
    const float* b_e2b = (const float*)d_in[15];
    const float* W_na  = (const float*)d_in[16];
    const float* b_na  = (const float*)d_in[17];
    const float* W_nb  = (const float*)d_in[18];
    const float* b_nb  = (const float*)d_in[19];
    const float* W_oa  = (const float*)d_in[20];
    const float* b_oa  = (const float*)d_in[21];
    const float* W_ob  = (const float*)d_in[22];
    const float* b_ob  = (const float*)d_in[23];

    const int* src = eidx;
    const int* dst = eidx + Ee;

    const size_t NHf = (size_t)Nn * Hh * sizeof(float);
    const size_t NHb = (size_t)Nn * Hh * sizeof(unsigned short);
    char* w = (char*)d_ws;
    unsigned short* hb0   = (unsigned short*)w; w += NHb;
    unsigned short* hb1   = (unsigned short*)w; w += NHb;
    float* agg2   = (float*)w; w += NHf;
    unsigned short* agg2b = (unsigned short*)w; w += NHb;
    float* aggr   = (float*)w; w += NHf;
    float* pooled = (float*)w; w += (size_t)Gg * Hh * sizeof(float);
    float* cntg   = (float*)w; w += (size_t)Gg * sizeof(float);
    int*   qlist  = (int*)w;   w += (size_t)Qq * sizeof(int);
    int*   perm_e = (int*)w;   w += (size_t)Ee * sizeof(int);
    int*   hist   = (int*)w;   w += (size_t)Nn * sizeof(int);
    int*   cursor = (int*)w;   w += (size_t)Nn * sizeof(int);
    int*   qcnt   = (int*)w;   w += 16;
    unsigned short* wbuf = (unsigned short*)w;   // 3 layers x 135168 bf16

    const size_t LSTRIDE = 135168;
    const size_t oWq1 = 0, oWq2 = 20480, oWe1 = 36864, oWe2 = 69632, oWn1 = 86016, oWn2 = 118784;

    // --- counting sort: edges by dst ---
    hipMemsetAsync(hist, 0, Nn * sizeof(int), stream);
    k_hist<<<(Ee + 255) / 256, 256, 0, stream>>>(dst, Ee, Nn, hist);
    k_scan<<<1, 1024, 0, stream>>>(hist, cursor, (int*)nullptr);
    k_scatter<<<(Ee + 255) / 256, 256, 0, stream>>>(dst, Ee, Nn, cursor, perm_e);
    // --- counting sort: quadruplets by k_idx, fused with compaction (k<Nn) ---
    hipMemsetAsync(hist, 0, Nn * sizeof(int), stream);
    k_hist<<<(Qq + 255) / 256, 256, 0, stream>>>(k_idx, Qq, Nn, hist);
    k_scan<<<1, 1024, 0, stream>>>(hist, cursor, qcnt);
    k_scatter<<<(Qq + 255) / 256, 256, 0, stream>>>(k_idx, Qq, Nn, cursor, qlist);

    k_h0<<<(Nn * Hh + 255) / 256, 256, 0, stream>>>(x, hb0);

    for (int p = 0; p < 3; ++p) {
        unsigned short* base = wbuf + p * LSTRIDE;
        k_wt<<<(128 * 160 + 255) / 256, 256, 0, stream>>>(W_e1a + (size_t)p * 146 * 128, base + oWq1, 146, 160);
        k_wt<<<(128 * 128 + 255) / 256, 256, 0, stream>>>(W_e1b + (size_t)p * 128 * 128, base + oWq2, 128, 128);
        k_wt<<<(128 * 256 + 255) / 256, 256, 0, stream>>>(W_e2a + (size_t)p * 256 * 128, base + oWe1, 256, 256);
        k_wt<<<(128 * 128 + 255) / 256, 256, 0, stream>>>(W_e2b + (size_t)p * 128 * 128, base + oWe2, 128, 128);
        k_wt<<<(128 * 256 + 255) / 256, 256, 0, stream>>>(W_na  + (size_t)p * 256 * 128, base + oWn1, 256, 256);
        k_wt<<<(128 * 128 + 255) / 256, 256, 0, stream>>>(W_nb  + (size_t)p * 128 * 128, base + oWn2, 128, 128);
    }

    unsigned short* bufs[2] = { hb0, hb1 };
    int cur = 0;
    for (int p = 0; p < 3; ++p) {
        unsigned short* base = wbuf + p * LSTRIDE;
        hipMemsetAsync(agg2, 0, NHf, stream);
        hipMemsetAsync(aggr, 0, NHf, stream);
        k_quad<<<2048, 256, 0, stream>>>(bufs[cur], rbf, cbf, sbf, l_idx, k_idx,
            qlist, qcnt,
            base + oWq1, b_e1a + (size_t)p * 128,
            base + oWq2, b_e1b + (size_t)p * 128, agg2);
        k_cvt<<<(Nn * Hh / 4 + 255) / 256, 256, 0, stream>>>(agg2, agg2b, Nn * Hh);
        k_edge<<<Ee / 64, 256, 0, stream>>>(bufs[cur], agg2b, src, dst, perm_e,
            base + oWe1, b_e2a + (size_t)p * 128,
            base + oWe2, b_e2b + (size_t)p * 128, aggr);
        k_node<<<(Nn + 63) / 64, 256, 0, stream>>>(bufs[cur], aggr,
            base + oWn1, b_na + (size_t)p * 128,
            base + oWn2, b_nb + (size_t)p * 128, bufs[cur ^ 1]);
        cur ^= 1;
    }
    hipMemsetAsync(pooled, 0, (size_t)Gg * Hh * sizeof(float), stream);
    hipMemsetAsync(cntg, 0, (size_t)Gg * sizeof(float), stream);
    k_pool<<<(Nn + 195) / 196, 256, 0, stream>>>(bufs[cur], batch, pooled, cntg);
    k_final<<<Gg, 128, 0, stream>>>(pooled, cntg, W_oa, b_oa, W_ob, b_ob, (float*)d_out);
}